// Round 5
// baseline (235.099 us; speedup 1.0000x reference)
//
#include <hip/hip_runtime.h>

// Adaptive embedding: partition tokens by cluster (wave-aggregated atomics),
// then gathered bf16-MFMA GEMM per cluster.
//   out[tok,:] = 32 * emb_c[id] @ proj_c^T   (fp32 in, bf16 MFMA, fp32 out)
//
// Round-5 structure (provable-sync version of the glds pipeline):
//  - fp32 LDS staging via global_load_lds (sink-proof prefetch: no dest regs).
//  - T3-minimum 2-phase schedule: issue(k+1 -> buf^1); compute(buf);
//    __syncthreads().  One barrier per chunk; prefetch overlaps compute;
//    sync is full-drain -> race-free by construction (R4's counted-vmcnt
//    3-buffer variant raced: absmax 0.22).
//  - XOR-swizzled LDS (16B block W holds logical (row=W>>3, kblk=(W&7)^(row&7))):
//    glds writes linear, source pre-swizzled, reads swizzled -> conflict-floor.
//  - 64x64 tiles, 4 waves (2x2).  No split-K, no atomics.
//  - flat slot grid decoded from cnt[]; c0 slots first; y-stride 264 % 8 == 0
//    keeps an m-tile's n-blocks on one XCD (gathered emb rows L2-local).
//
// d_in[0] ids i32[16384]; (emb_i f32[*,d_i], proj_i f32[1024,d_i]), d_i=1024/256/64/16
// out f32 [16384,1024]. ws: int cnt[4]; int lists[4][16384].

constexpr int NTOK  = 16384;
constexpr int DPROJ = 1024;
constexpr float EMB_SCALE = 32.0f;
constexpr int SLOTX = 264;    // >= worst-case slots (256+4), multiple of 8

typedef __attribute__((ext_vector_type(8))) short short8;   // 8 bf16
typedef __attribute__((ext_vector_type(4))) float float4v;  // MFMA C/D

__global__ __launch_bounds__(256) void partition_kernel(
    const int* __restrict__ ids, int* __restrict__ cnt, int* __restrict__ lists)
{
    int t = blockIdx.x * 256 + threadIdx.x;
    int id = ids[t];
    int c = (id >= 200000) ? 3 : (id >= 40000) ? 2 : (id >= 20000) ? 1 : 0;
    int lane = threadIdx.x & 63;
    unsigned long long lt = (1ull << lane) - 1ull;
    int pos = 0;
#pragma unroll
    for (int i = 0; i < 4; ++i) {
        unsigned long long m = __ballot(c == i);
        int b = 0;
        if (lane == 0 && m) b = atomicAdd(&cnt[i], (int)__popcll(m));
        b = __shfl(b, 0);
        if (c == i) pos = b + (int)__popcll(m & lt);
    }
    lists[c * NTOK + pos] = t;
}

__device__ __forceinline__ void gload_lds16(const float* g, void* l) {
    __builtin_amdgcn_global_load_lds(
        (const __attribute__((address_space(1))) void*)g,
        (__attribute__((address_space(3))) void*)l, 16, 0, 0);
}

__device__ __forceinline__ short f2bf(float f) {  // RNE; inputs finite
    unsigned u = __builtin_bit_cast(unsigned, f);
    u += 0x7FFFu + ((u >> 16) & 1u);
    return (short)(u >> 16);
}

__device__ __forceinline__ short8 cvt8f(float4 a, float4 b) {
    short8 r = { f2bf(a.x), f2bf(a.y), f2bf(a.z), f2bf(a.w),
                 f2bf(b.x), f2bf(b.y), f2bf(b.z), f2bf(b.w) };
    return r;
}

// 64(tokens) x 64(cols) tile, 4 waves in 2x2; wave -> 32x32 sub-tile.
// LDS: fp32 A[64][32] and B[64][32] per buffer, 2 buffers (32 KB).
// Swizzle: 16B block W holds logical (row=W>>3, kblk=(W&7)^(row&7)).
template<int D, int NC>
__device__ __forceinline__ void gemm_pipe(
    const int* __restrict__ ids, const float* __restrict__ emb,
    const float* __restrict__ proj, const int* __restrict__ list,
    int count, int lo, int mtile, int n0,
    float* __restrict__ out, char* smem, int* smTok, int* smRow)
{
    const int m0 = mtile * 64;
    if (m0 >= count) return;
    const int tid = threadIdx.x, lane = tid & 63, wv = tid >> 6;
    const int col = lane & 15, quad = lane >> 4;
    const int wr = (wv >> 1) * 32, wc = (wv & 1) * 32;

    if (tid < 64) {
        int m = m0 + tid;
        int tok = (m < count) ? list[m] : -1;
        smTok[tid] = tok;
        smRow[tid] = (tok >= 0) ? (ids[tok] - lo) : 0;
    }
    __syncthreads();

    float (*As)[2048] = (float(*)[2048])smem;              // 2 x 8 KB
    float (*Bs)[2048] = (float(*)[2048])(smem + 2 * 8192); // 2 x 8 KB

    // glds: dest = linear (wave base + lane*16); source pre-swizzled so that
    // physical 16B block W = L>>4 holds logical (row=W>>3, kblk=(W&7)^(row&7)).
    const float* srcA[2]; const float* srcB[2]; int LL[2];
#pragma unroll
    for (int i = 0; i < 2; ++i) {
        int L = i * 4096 + wv * 1024 + lane * 16;          // byte in 8 KB tile
        int row = L >> 7;                                  // 0..63
        int kblk = ((L >> 4) & 7) ^ (row & 7);             // inverse swizzle
        LL[i] = L;
        srcA[i] = emb  + (size_t)smRow[row] * D + kblk * 4;
        srcB[i] = proj + (size_t)(n0 + row) * D + kblk * 4;
    }

    auto issue = [&](int c, int buf) {   // 4 glds/thread/chunk
        const int co = c * 32;
#pragma unroll
        for (int i = 0; i < 2; ++i) gload_lds16(srcA[i] + co, (char*)As[buf] + LL[i]);
#pragma unroll
        for (int i = 0; i < 2; ++i) gload_lds16(srcB[i] + co, (char*)Bs[buf] + LL[i]);
    };

    float4v acc[2][2] = {};
    auto compute = [&](int buf) {
        short8 af[2], bf[2];
#pragma unroll
        for (int m = 0; m < 2; ++m) {
            int row = wr + m * 16 + col;
            const float* Ab = As[buf] + row * 32;
            float4 x = *(const float4*)(Ab + (((2 * quad + 0) ^ (row & 7)) << 2));
            float4 y = *(const float4*)(Ab + (((2 * quad + 1) ^ (row & 7)) << 2));
            af[m] = cvt8f(x, y);
        }
#pragma unroll
        for (int n = 0; n < 2; ++n) {
            int row = wc + n * 16 + col;
            const float* Bb = Bs[buf] + row * 32;
            float4 x = *(const float4*)(Bb + (((2 * quad + 0) ^ (row & 7)) << 2));
            float4 y = *(const float4*)(Bb + (((2 * quad + 1) ^ (row & 7)) << 2));
            bf[n] = cvt8f(x, y);
        }
#pragma unroll
        for (int m = 0; m < 2; ++m)
#pragma unroll
            for (int n = 0; n < 2; ++n)
                acc[m][n] = __builtin_amdgcn_mfma_f32_16x16x32_bf16(
                    af[m], bf[n], acc[m][n], 0, 0, 0);
    };

    // T3-minimum 2-phase pipeline: prefetch next chunk during current compute;
    // __syncthreads() = full drain (vmcnt 0 + lgkmcnt 0) + barrier -> race-free.
    issue(0, 0);
    __syncthreads();
#pragma unroll
    for (int k = 0; k < NC; ++k) {
        if (k + 1 < NC) issue(k + 1, (k + 1) & 1);
        compute(k & 1);
        __syncthreads();
    }

    // C/D layout: col = lane&15, row = quad*4 + reg
#pragma unroll
    for (int m = 0; m < 2; ++m) {
#pragma unroll
        for (int r = 0; r < 4; ++r) {
            int tok = smTok[wr + m * 16 + quad * 4 + r];
            if (tok < 0) continue;
            float* op = out + (size_t)tok * DPROJ + n0 + wc + col;
            op[0]  = acc[m][0][r] * EMB_SCALE;
            op[16] = acc[m][1][r] * EMB_SCALE;
        }
    }
}

// Cluster 3 (D=16): single K<32 chunk; reg-staged bf16 LDS, frags for
// quad>=2 (k>=16) are zero so no K padding is stored.
__device__ __forceinline__ void gemm_c3(
    const int* __restrict__ ids, const float* __restrict__ emb,
    const float* __restrict__ proj, const int* __restrict__ list,
    int count, int mtile, int n0,
    float* __restrict__ out, char* smem, int* smTok, int* smRow)
{
    const int m0 = mtile * 64;
    if (m0 >= count) return;
    const int tid = threadIdx.x, lane = tid & 63, wv = tid >> 6;
    const int col = lane & 15, quad = lane >> 4;
    const int wr = (wv >> 1) * 32, wc = (wv & 1) * 32;
    short (*Asm)[24] = (short(*)[24])smem;                  // 64x24 bf16
    short (*Bsm)[24] = (short(*)[24])(smem + 64 * 24 * 2);

    if (tid < 64) {
        int m = m0 + tid;
        int tok = (m < count) ? list[m] : -1;
        smTok[tid] = tok;
        smRow[tid] = (tok >= 0) ? (ids[tok] - 200000) : 0;
    }
    __syncthreads();

    if (tid < 128) {            // A: 64 rows x 16 f
        int r = tid >> 1, c0 = (tid & 1) * 8;
        const float* p = emb + (size_t)smRow[r] * 16 + c0;
        float4 x = *(const float4*)p, y = *(const float4*)(p + 4);
        *(short8*)&Asm[r][c0] = cvt8f(x, y);
    } else {                    // B: 64 rows x 16 f
        int t = tid - 128, r = t >> 1, c0 = (t & 1) * 8;
        const float* p = proj + (size_t)(n0 + r) * 16 + c0;
        float4 x = *(const float4*)p, y = *(const float4*)(p + 4);
        *(short8*)&Bsm[r][c0] = cvt8f(x, y);
    }
    __syncthreads();

    short8 z8 = {};
    short8 af[2], bf[2];
#pragma unroll
    for (int m = 0; m < 2; ++m)
        af[m] = (quad < 2) ? *(const short8*)&Asm[wr + m * 16 + col][quad * 8] : z8;
#pragma unroll
    for (int n = 0; n < 2; ++n)
        bf[n] = (quad < 2) ? *(const short8*)&Bsm[wc + n * 16 + col][quad * 8] : z8;

    float4v acc[2][2] = {};
#pragma unroll
    for (int m = 0; m < 2; ++m)
#pragma unroll
        for (int n = 0; n < 2; ++n)
            acc[m][n] = __builtin_amdgcn_mfma_f32_16x16x32_bf16(
                af[m], bf[n], acc[m][n], 0, 0, 0);

#pragma unroll
    for (int m = 0; m < 2; ++m) {
#pragma unroll
        for (int r = 0; r < 4; ++r) {
            int tok = smTok[wr + m * 16 + quad * 4 + r];
            if (tok < 0) continue;
            float* op = out + (size_t)tok * DPROJ + n0 + wc + col;
            op[0]  = acc[m][0][r] * EMB_SCALE;
            op[16] = acc[m][1][r] * EMB_SCALE;
        }
    }
}

__global__ __launch_bounds__(256) void adaptive_emb_gemm(
    const int* __restrict__ ids,
    const float* __restrict__ e0, const float* __restrict__ p0,
    const float* __restrict__ e1, const float* __restrict__ p1,
    const float* __restrict__ e2, const float* __restrict__ p2,
    const float* __restrict__ e3, const float* __restrict__ p3,
    const int* __restrict__ cnt, const int* __restrict__ lists,
    float* __restrict__ out)
{
    __shared__ __align__(16) char smem[32768];   // 2 bufs x (8K A + 8K B)
    __shared__ int smTok[64], smRow[64];

    const int n0 = blockIdx.y * 64;
    int c0t = (cnt[0] + 63) >> 6;
    int c1t = (cnt[1] + 63) >> 6;
    int c2t = (cnt[2] + 63) >> 6;
    int c3t = (cnt[3] + 63) >> 6;
    int s = blockIdx.x;
    if (s < c0t) {
        gemm_pipe<1024, 32>(ids, e0, p0, lists, cnt[0], 0,
                            s, n0, out, smem, smTok, smRow);
        return;
    }
    s -= c0t;
    if (s < c1t) {
        gemm_pipe<256, 8>(ids, e1, p1, lists + NTOK, cnt[1], 20000,
                          s, n0, out, smem, smTok, smRow);
        return;
    }
    s -= c1t;
    if (s < c2t) {
        gemm_pipe<64, 2>(ids, e2, p2, lists + 2 * NTOK, cnt[2], 40000,
                         s, n0, out, smem, smTok, smRow);
        return;
    }
    s -= c2t;
    if (s < c3t)
        gemm_c3(ids, e3, p3, lists + 3 * NTOK, cnt[3], s, n0, out, smem, smTok, smRow);
}

extern "C" void kernel_launch(void* const* d_in, const int* in_sizes, int n_in,
                              void* d_out, int out_size, void* d_ws, size_t ws_size,
                              hipStream_t stream) {
    const int*   ids = (const int*)d_in[0];
    const float* e0  = (const float*)d_in[1];
    const float* p0  = (const float*)d_in[2];
    const float* e1  = (const float*)d_in[3];
    const float* p1  = (const float*)d_in[4];
    const float* e2  = (const float*)d_in[5];
    const float* p2  = (const float*)d_in[6];
    const float* e3  = (const float*)d_in[7];
    const float* p3  = (const float*)d_in[8];
    float* out = (float*)d_out;

    int* cnt   = (int*)d_ws;
    int* lists = cnt + 4;

    (void)hipMemsetAsync(cnt, 0, 4 * sizeof(int), stream);
    partition_kernel<<<dim3(NTOK / 256), 256, 0, stream>>>(ids, cnt, lists);

    // x = flat slot (cluster/m-tile decoded from cnt[] on device, c0 first),
    // y = n-tile (16 x 64 cols).  y-stride in linear block id = 264 (mult of
    // 8) -> one m-tile's n-blocks land on one XCD -> emb gather is L2-local.
    adaptive_emb_gemm<<<dim3(SLOTX, DPROJ / 64), 256, 0, stream>>>(
        ids, e0, p0, e1, p1, e2, p2, e3, p3, cnt, lists, out);
}